// Round 4
// baseline (257384.692 us; speedup 1.0000x reference)
//
#include <hip/hip_runtime.h>
#include <cmath>

// Problem dims (fixed): T=4096, I=512, H=2048, F=256
#define NSTEP 8191   // 4096 enc + 4095 dec

// ---------------- small kernels ----------------
__global__ void fillK(float* p, int n, float v){
  for (int i = blockIdx.x*blockDim.x + threadIdx.x; i < n; i += gridDim.x*blockDim.x) p[i] = v;
}

__global__ void copyK(float* dst, const float* __restrict__ src, int n){
  int i = blockIdx.x*blockDim.x + threadIdx.x;
  if (i < n) dst[i] = src[i];
}

// coalesced 2-pass mean: mean[i] = sum_t seq[t,i] / (1e-6 + count_t(mask!=0))
__global__ void mean1K(const float* __restrict__ seq, const float* __restrict__ mask,
                       float* __restrict__ Sp, float* __restrict__ Cp){
  int bb = blockIdx.x, i = threadIdx.x;      // 64 blocks x 512 threads
  float s = 0.f, c = 0.f;
  for (int tt = 64*bb; tt < 64*bb + 64; ++tt){
    size_t o = (size_t)tt*512 + i;
    s += seq[o];
    c += (mask[o] != 0.f) ? 1.f : 0.f;
  }
  Sp[bb*512 + i] = s; Cp[bb*512 + i] = c;
}
__global__ void mean2K(const float* __restrict__ Sp, const float* __restrict__ Cp,
                       float* __restrict__ meanv){
  int i = threadIdx.x;                        // 1 block x 512
  float s = 0.f, c = 0.f;
  for (int bb = 0; bb < 64; ++bb){ s += Sp[bb*512 + i]; c += Cp[bb*512 + i]; }
  meanv[i] = s / (1e-6f + c);
}

// ---------------- parallel affine scan for prex/xh recurrence ----------------
// xh[r] = a[r]*xh[r-1] + c[r];  a=(1-m)*g, c=m*x+(1-m)*(1-g)*mn; src map enc/dec.
__device__ __forceinline__ void scan_ac(const float* __restrict__ Gx,
                                        const float* __restrict__ mask,
                                        const float* __restrict__ seq,
                                        float mn, int r, int i, float& a, float& c){
  int src = (r < 4096) ? r : (8190 - r);
  size_t o = (size_t)src*512 + i;
  float g = Gx[o], m = mask[o], x = seq[o];
  a = (1.f - m)*g;
  c = m*x + (1.f - m)*(1.f - g)*mn;
}
__global__ void scanSegK(const float* __restrict__ Gx, const float* __restrict__ mask,
                         const float* __restrict__ seq, const float* __restrict__ meanv,
                         float* __restrict__ segA, float* __restrict__ segC){
  int bb = blockIdx.x, i = threadIdx.x;       // 64 blocks x 512 threads
  float mn = meanv[i];
  float A = 1.f, C = 0.f;
  int r1 = 128*bb + 128; if (r1 > NSTEP) r1 = NSTEP;
  for (int r = 128*bb; r < r1; ++r){
    float a, c; scan_ac(Gx, mask, seq, mn, r, i, a, c);
    A = a*A; C = a*C + c;
  }
  segA[bb*512 + i] = A; segC[bb*512 + i] = C;
}
__global__ void scanFixK(const float* __restrict__ segA, const float* __restrict__ segC,
                         const float* __restrict__ prex0, float* __restrict__ segX0){
  int i = threadIdx.x;                        // 1 block x 512
  float x = prex0[i];
  for (int bb = 0; bb < 64; ++bb){
    segX0[bb*512 + i] = x;
    x = segA[bb*512 + i]*x + segC[bb*512 + i];
  }
}
__global__ void scanEmitK(const float* __restrict__ Gx, const float* __restrict__ mask,
                          const float* __restrict__ seq, const float* __restrict__ meanv,
                          const float* __restrict__ segX0, float* __restrict__ xh){
  int bb = blockIdx.x, i = threadIdx.x;
  float mn = meanv[i];
  float x = segX0[bb*512 + i];
  int r1 = 128*bb + 128; if (r1 > NSTEP) r1 = NSTEP;
  for (int r = 128*bb; r < r1; ++r){
    float a, c; scan_ac(Gx, mask, seq, mn, r, i, a, c);
    x = a*x + c;
    xh[(size_t)r*512 + i] = x;
  }
}

// ---------------- generic fp32 GEMM: C = act(A@B + bias) [+ C if beta] ----------
// A: M x K (lda=K), B: K x N row-major. act: 0 none, 1 exp(-relu(x)).
// amap=1: A row r reads source row map(rowoff+r), map(g)=g<4096?g:8190-g.
#define BM 128
#define BN 128
#define BK 8
__launch_bounds__(256)
__global__ void gemmK(const float* __restrict__ A, const float* __restrict__ B,
                      float* __restrict__ C, int M, int N, int K,
                      const float* __restrict__ bias, int act, int beta, int amap,
                      int rowoff){
  __shared__ float As[BK][BM+4];
  __shared__ float Bs[BK][BN+4];
  int tid = threadIdx.x;
  int r0 = blockIdx.y * BM, c0 = blockIdx.x * BN;
  int tr = tid >> 4, tc = tid & 15;
  int ar = tid >> 1, ak = (tid & 1)*4;
  int bkr = tid >> 5, bkc = (tid & 31)*4;
  float acc[8][8] = {};

  for (int k0 = 0; k0 < K; k0 += BK){
    int r = r0 + ar;
    float4 av = make_float4(0.f,0.f,0.f,0.f);
    if (r < M){
      int g = rowoff + r;
      int rs = amap ? (g < 4096 ? g : 8190 - g) : r;
      av = *(const float4*)(A + (size_t)rs*K + k0 + ak);
    }
    As[ak+0][ar] = av.x; As[ak+1][ar] = av.y; As[ak+2][ar] = av.z; As[ak+3][ar] = av.w;
    *(float4*)(&Bs[bkr][bkc]) = *(const float4*)(B + (size_t)(k0 + bkr)*N + c0 + bkc);
    __syncthreads();
    #pragma unroll
    for (int kk = 0; kk < BK; ++kk){
      float a[8], bb[8];
      #pragma unroll
      for (int i = 0; i < 8; ++i) a[i]  = As[kk][tr*8 + i];
      #pragma unroll
      for (int j = 0; j < 8; ++j) bb[j] = Bs[kk][tc*8 + j];
      #pragma unroll
      for (int i = 0; i < 8; ++i)
        #pragma unroll
        for (int j = 0; j < 8; ++j)
          acc[i][j] += a[i]*bb[j];
    }
    __syncthreads();
  }

  #pragma unroll
  for (int i = 0; i < 8; ++i){
    int r = r0 + tr*8 + i;
    if (r >= M) continue;
    float v[8];
    #pragma unroll
    for (int j = 0; j < 8; ++j){
      int c = c0 + tc*8 + j;
      float x = acc[i][j];
      if (bias) x += bias[c];
      if (act == 1) x = expf(-fmaxf(x, 0.f));
      v[j] = x;
    }
    float* cp = C + (size_t)r*N + c0 + tc*8;
    if (beta){
      float4 o0 = *(const float4*)(cp);
      float4 o1 = *(const float4*)(cp + 4);
      v[0]+=o0.x; v[1]+=o0.y; v[2]+=o0.z; v[3]+=o0.w;
      v[4]+=o1.x; v[5]+=o1.y; v[6]+=o1.z; v[7]+=o1.w;
    }
    *(float4*)(cp)     = make_float4(v[0],v[1],v[2],v[3]);
    *(float4*)(cp + 4) = make_float4(v[4],v[5],v[6],v[7]);
  }
}

// ---------------- per-step kernels (no cross-WG sync anywhere) ----------------
// stepA: zr = sigmoid(pre + (gh*h)@U[:, :4096]); writes z (2048) and rhd=r*hd (2048).
// Grid 256 WGs x 256 thr; WG w owns cols j=16w..16w+15; thread=(ko=t>>4, jo=t&15),
// each sums 128 k. U col j read at stride 6144 -> 16 lanes x 4B = 64B segments.
__launch_bounds__(256)
__global__ void stepAK(const float* __restrict__ U, const float* __restrict__ pre,
                       const float* __restrict__ ghrow, const float* __restrict__ hbuf,
                       float* __restrict__ zbuf, float* __restrict__ rhdbuf){
  __shared__ float hdl[2048];
  __shared__ float red[16][17];
  int w = blockIdx.x, t = threadIdx.x;
  for (int i = t; i < 2048; i += 256) hdl[i] = hbuf[i] * ghrow[i];
  __syncthreads();
  int jo = t & 15, ko = t >> 4;
  const float* Ucol = U + 16*w + jo;
  float s = 0.f;
  int k0 = ko*128;
  #pragma unroll 4
  for (int k = k0; k < k0 + 128; ++k) s += hdl[k] * Ucol[(size_t)k*6144];
  red[ko][jo] = s;
  __syncthreads();
  if (t < 16){
    float a = 0.f;
    #pragma unroll
    for (int q = 0; q < 16; ++q) a += red[q][t];
    int j = 16*w + t;
    float v = 1.f/(1.f + expf(-(pre[j] + a)));
    if (j < 2048) zbuf[j] = v;
    else          rhdbuf[j - 2048] = v * hdl[j - 2048];
  }
}

// stepB: htil = tanh(prh + rhd@U[:, 4096:]); h += dt*dh; hp out (+HpDec row if dec).
// Grid 128 WGs x 256 thr; WG w owns j=16w..16w+15.
__launch_bounds__(256)
__global__ void stepBK(const float* __restrict__ U, const float* __restrict__ prh,
                       const float* __restrict__ ghrow, const float* __restrict__ dtp,
                       const float* __restrict__ zbuf, const float* __restrict__ rhdbuf,
                       float* __restrict__ hbuf, float* __restrict__ hpbuf,
                       float* __restrict__ hpdec){
  __shared__ float rl[2048];
  __shared__ float red[16][17];
  int w = blockIdx.x, t = threadIdx.x;
  for (int i = t; i < 2048; i += 256) rl[i] = rhdbuf[i];
  __syncthreads();
  int jo = t & 15, ko = t >> 4;
  const float* Ucol = U + 4096 + 16*w + jo;
  float s = 0.f;
  int k0 = ko*128;
  #pragma unroll 4
  for (int k = k0; k < k0 + 128; ++k) s += rl[k] * Ucol[(size_t)k*6144];
  red[ko][jo] = s;
  __syncthreads();
  if (t < 16){
    float a = 0.f;
    #pragma unroll
    for (int q = 0; q < 16; ++q) a += red[q][t];
    int j = 16*w + t;
    float htil = tanhf(prh[j] + a);
    float z    = zbuf[j];
    float hold = hbuf[j];
    float hd   = hold * ghrow[j];
    float hp   = z*hd + (1.f - z)*htil;
    float dh   = (1.f - z)*(htil - hd);
    hbuf[j]  = hold + dtp[0]*dh;
    hpbuf[j] = hp;
    if (hpdec) hpdec[j] = hp;
  }
}

// mid-MLP kernel 1: feature[f] = relu( relu(hp) @ We + be )  (F=256, K=2048)
__launch_bounds__(256)
__global__ void mlp1K(const float* __restrict__ hpbuf, const float* __restrict__ We,
                      const float* __restrict__ be, float* __restrict__ featbuf){
  __shared__ float red[16][17];
  int w = blockIdx.x, t = threadIdx.x;      // 16 WGs
  int fo = t & 15, ko = t >> 4;
  int f = 16*w + fo;
  float s = 0.f;
  int k0 = ko*128;
  for (int k = k0; k < k0 + 128; ++k)
    s += fmaxf(hpbuf[k], 0.f) * We[(size_t)k*256 + f];
  red[ko][fo] = s;
  __syncthreads();
  if (t < 16){
    float a = 0.f;
    #pragma unroll
    for (int q = 0; q < 16; ++q) a += red[q][t];
    featbuf[16*w + t] = fmaxf(a + be[16*w + t], 0.f);
  }
}
// mid-MLP kernel 2: h[j] = feature @ Wd + bd  (H=2048, K=256)
__launch_bounds__(256)
__global__ void mlp2K(const float* __restrict__ featbuf, const float* __restrict__ Wd,
                      const float* __restrict__ bd, float* __restrict__ hbuf){
  __shared__ float red[16][17];
  int w = blockIdx.x, t = threadIdx.x;      // 128 WGs
  int jo = t & 15, ko = t >> 4;
  int j = 16*w + jo;
  float s = 0.f;
  int k0 = ko*16;
  for (int k = k0; k < k0 + 16; ++k)
    s += featbuf[k] * Wd[(size_t)k*2048 + j];
  red[ko][jo] = s;
  __syncthreads();
  if (t < 16){
    float a = 0.f;
    #pragma unroll
    for (int q = 0; q < 16; ++q) a += red[q][t];
    hbuf[16*w + t] = a + bd[16*w + t];
  }
}

// ---------------- launch ----------------
extern "C" void kernel_launch(void* const* d_in, const int* in_sizes, int n_in,
                              void* d_out, int out_size, void* d_ws, size_t ws_size,
                              hipStream_t stream){
  (void)in_sizes; (void)n_in;
  const float* seq   = (const float*)d_in[0];
  const float* mask  = (const float*)d_in[1];
  const float* delta = (const float*)d_in[2];
  const float* dt    = (const float*)d_in[3];
  const float* h0    = (const float*)d_in[4];
  /* d_in[5] = dh0: carried dh never read by the reference cell */
  const float* prex0 = (const float*)d_in[6];
  const float* Wgx   = (const float*)d_in[7];
  const float* bgx   = (const float*)d_in[8];
  const float* Wgh   = (const float*)d_in[9];
  const float* bgh   = (const float*)d_in[10];
  const float* W     = (const float*)d_in[11];
  const float* U     = (const float*)d_in[12];
  const float* V     = (const float*)d_in[13];
  const float* b     = (const float*)d_in[14];
  const float* We    = (const float*)d_in[15];
  const float* be    = (const float*)d_in[16];
  const float* Wd    = (const float*)d_in[17];
  const float* bd    = (const float*)d_in[18];
  const float* Wo    = (const float*)d_in[19];
  const float* bo    = (const float*)d_in[20];

  float* wsf = (float*)d_ws;
  size_t wsFloats = ws_size / 4;
  size_t off = 0;
  float* meanv  = wsf + off;  off += 512;
  float* hbuf   = wsf + off;  off += 2048;
  float* zbuf   = wsf + off;  off += 2048;
  float* rhdbuf = wsf + off;  off += 2048;
  float* hpbuf  = wsf + off;  off += 2048;
  float* featbuf= wsf + off;  off += 256;
  float* Sp     = wsf + off;  off += (size_t)64*512;
  float* Cp     = wsf + off;  off += (size_t)64*512;
  float* Gh     = wsf + off;  off += (size_t)4096*2048;
  float* xh_all = wsf + off;  off += (size_t)NSTEP*512;
  float* HpDec  = wsf + off;  off += (size_t)4095*2048;
  size_t fixedF = off;

  // chunk area: overlays {Gx, scan temps} during precompute, PreTab chunk after
  float* area  = wsf + fixedF;
  float* Gx    = area;                                   // 4096*512
  float* segA  = area + (size_t)4096*512;                // 64*512
  float* segC  = segA + (size_t)64*512;
  float* segX0 = segC + (size_t)64*512;
  size_t preNeed = (size_t)4096*512 + (size_t)3*64*512;

  size_t areaF = (wsFloats > fixedF) ? (wsFloats - fixedF) : 0;
  long chunkSteps = (long)(areaF / 6144);
  if (areaF < preNeed || chunkSteps < 64){
    // informative sentinel: absmax ~= 1e6 + ws_MB reveals the actual budget
    fillK<<<dim3(256), dim3(256), 0, stream>>>((float*)d_out, out_size,
                                               1.0e6f + (float)(ws_size >> 20));
    return;
  }
  if (chunkSteps > NSTEP) chunkSteps = NSTEP;
  int nch  = (int)((NSTEP + chunkSteps - 1) / chunkSteps);
  int clen = (NSTEP + nch - 1) / nch;

  // ---- precompute ----
  mean1K<<<dim3(64), dim3(512), 0, stream>>>(seq, mask, Sp, Cp);
  mean2K<<<dim3(1),  dim3(512), 0, stream>>>(Sp, Cp, meanv);
  gemmK<<<dim3(4, 32),  dim3(256), 0, stream>>>(delta, Wgx, Gx, 4096, 512, 512, bgx, 1, 0, 0, 0);
  gemmK<<<dim3(16, 32), dim3(256), 0, stream>>>(delta, Wgh, Gh, 4096, 2048, 512, bgh, 1, 0, 0, 0);
  scanSegK<<<dim3(64), dim3(512), 0, stream>>>(Gx, mask, seq, meanv, segA, segC);
  scanFixK<<<dim3(1),  dim3(512), 0, stream>>>(segA, segC, prex0, segX0);
  scanEmitK<<<dim3(64), dim3(512), 0, stream>>>(Gx, mask, seq, meanv, segX0, xh_all);
  copyK<<<dim3(8), dim3(256), 0, stream>>>(hbuf, h0, 2048);

  // ---- chunked recurrence: [PreTab GEMMs] then per-step kernel pairs ----
  for (int c0 = 0; c0 < NSTEP; c0 += clen){
    int len = (c0 + clen <= NSTEP) ? clen : (NSTEP - c0);
    int gy  = (len + 127) / 128;
    gemmK<<<dim3(48, gy), dim3(256), 0, stream>>>(xh_all + (size_t)c0*512, W, area,
                                                  len, 6144, 512, b, 0, 0, 0, 0);
    gemmK<<<dim3(48, gy), dim3(256), 0, stream>>>(mask, V, area,
                                                  len, 6144, 512, nullptr, 0, 1, 1, c0);
    for (int sl = 0; sl < len; ++sl){
      int g = c0 + sl;
      if (g == 4096){
        mlp1K<<<dim3(16),  dim3(256), 0, stream>>>(hpbuf, We, be, featbuf);
        mlp2K<<<dim3(128), dim3(256), 0, stream>>>(featbuf, Wd, bd, hbuf);
      }
      int src = (g < 4096) ? g : (8190 - g);
      const float* prow  = area + (size_t)sl*6144;
      const float* ghrow = Gh + (size_t)src*2048;
      float* hpd = (g >= 4096) ? (HpDec + (size_t)(8190 - g)*2048) : nullptr;
      stepAK<<<dim3(256), dim3(256), 0, stream>>>(U, prow, ghrow, hbuf, zbuf, rhdbuf);
      stepBK<<<dim3(128), dim3(256), 0, stream>>>(U, prow + 4096, ghrow, dt + src,
                                                  zbuf, rhdbuf, hbuf, hpbuf, hpd);
    }
  }

  // out = HpDec @ Wo + bo : 4095x512, K=2048 (HpDec stored pre-reversed)
  gemmK<<<dim3(4, 32), dim3(256), 0, stream>>>(HpDec, Wo, (float*)d_out,
                                               4095, 512, 2048, bo, 0, 0, 0, 0);
}